// Round 3
// baseline (878.315 us; speedup 1.0000x reference)
//
#include <hip/hip_runtime.h>
#include <cstdint>
#include <cstddef>

#define BB 4
#define TT 16384
#define CC 512
#define HH 8
#define DD 64
#define MTOT (BB*TT)   // 65536 token rows

typedef __attribute__((ext_vector_type(4))) float f32x4;
typedef __bf16 bf16;
typedef __attribute__((ext_vector_type(8))) bf16 bf16x8;
typedef __attribute__((ext_vector_type(4))) bf16 bf16x4;

static __device__ __forceinline__ float b2f(bf16 x) { return (float)x; }
static __device__ __forceinline__ bf16  f2b(float x) { return (bf16)x; }

// ---------------------------------------------------------------------------
// Transpose+convert a 512x512 fp32 weight to bf16 Wt[n][k] = W[k][n].
// ---------------------------------------------------------------------------
__global__ __launch_bounds__(256) void transpose_w(const float* __restrict__ W,
                                                   bf16* __restrict__ Wt)
{
    __shared__ float tile[32][33];
    const int t = blockIdx.x;
    const int r0 = (t >> 4) * 32, c0 = (t & 15) * 32;
    const int tid = threadIdx.x;
    {
        int r = tid >> 3, c4 = (tid & 7) << 2;
        float4 v = *(const float4*)(W + (size_t)(r0 + r) * 512 + c0 + c4);
        tile[r][c4 + 0] = v.x; tile[r][c4 + 1] = v.y;
        tile[r][c4 + 2] = v.z; tile[r][c4 + 3] = v.w;
    }
    __syncthreads();
    {
        int n = tid >> 3, k4 = (tid & 7) << 2;
        bf16x4 o;
        o[0] = f2b(tile[k4 + 0][n]); o[1] = f2b(tile[k4 + 1][n]);
        o[2] = f2b(tile[k4 + 2][n]); o[3] = f2b(tile[k4 + 3][n]);
        *(bf16x4*)(Wt + (size_t)(c0 + n) * 512 + r0 + k4) = o;
    }
}

// ---------------------------------------------------------------------------
// Projection GEMM (MFMA, verified m97-structure).
// MODE 1: fp32 A, +bias, store bf16 (Q/K pre-softmax)
// MODE 2: two fp32 A / two weights (K=1024), +bias0+bias1, store bf16 (V)
// MODE 3: bf16 A, +bias, store fp32 (final out; m_base for phased launches)
// ---------------------------------------------------------------------------
template<int MODE>
__global__ __launch_bounds__(512) void gemm_proj(
    const float* A0, const float* A1, const bf16* Abf,
    const bf16* Wt0, const bf16* Wt1,
    const float* bias0, const float* bias1,
    bf16* outb, float* outf, int m_base)
{
    __shared__ bf16 Asm[64][40];
    __shared__ bf16 Bsm[512][40];

    const int tid = threadIdx.x;
    const int lane = tid & 63;
    const int w = tid >> 6;
    const int l15 = lane & 15, lg = lane >> 4;
    const size_t m0 = (size_t)(blockIdx.x + m_base) * 64;

    f32x4 acc[4][4];
#pragma unroll
    for (int m = 0; m < 4; ++m)
#pragma unroll
        for (int n = 0; n < 4; ++n) acc[m][n] = (f32x4){0.f, 0.f, 0.f, 0.f};

    const int KSTEPS = (MODE == 2) ? 32 : 16;
    for (int ko = 0; ko < KSTEPS; ++ko) {
        const int k0 = (ko & 15) * 32;
        const float* Af = (MODE == 2 && ko >= 16) ? A1 : A0;
        const bf16* Wt  = (MODE == 2 && ko >= 16) ? Wt1 : Wt0;
        __syncthreads();
        if (MODE == 3) {
            if (tid < 256) {
                int row = tid >> 2, c8 = (tid & 3) << 3;
                bf16x8 v = *(const bf16x8*)(Abf + (m0 + row) * CC + k0 + c8);
                *(bf16x8*)&Asm[row][c8] = v;
            }
        } else {
            int row = tid >> 3, c4 = (tid & 7) << 2;
            float4 v = *(const float4*)(Af + (m0 + row) * CC + k0 + c4);
            bf16x4 s;
            s[0] = f2b(v.x); s[1] = f2b(v.y); s[2] = f2b(v.z); s[3] = f2b(v.w);
            *(bf16x4*)&Asm[row][c4] = s;
        }
#pragma unroll
        for (int r = 0; r < 4; ++r) {
            int n = (tid >> 2) + (r << 7), kk = (tid & 3) << 3;
            bf16x8 v = *(const bf16x8*)(Wt + (size_t)n * CC + k0 + kk);
            *(bf16x8*)&Bsm[n][kk] = v;
        }
        __syncthreads();
        bf16x8 af[4], bfv[4];
#pragma unroll
        for (int m = 0; m < 4; ++m)
            af[m] = *(const bf16x8*)&Asm[m * 16 + l15][lg * 8];
#pragma unroll
        for (int n = 0; n < 4; ++n)
            bfv[n] = *(const bf16x8*)&Bsm[w * 64 + n * 16 + l15][lg * 8];
#pragma unroll
        for (int m = 0; m < 4; ++m)
#pragma unroll
            for (int n = 0; n < 4; ++n)
                acc[m][n] = __builtin_amdgcn_mfma_f32_16x16x32_bf16(
                    af[m], bfv[n], acc[m][n], 0, 0, 0);
    }

    float bias[4];
#pragma unroll
    for (int n = 0; n < 4; ++n) {
        int col = w * 64 + n * 16 + l15;
        float bvv = bias0 ? bias0[col] : 0.f;
        if (MODE == 2) bvv += bias1[col];
        bias[n] = bvv;
    }
#pragma unroll
    for (int m = 0; m < 4; ++m) {
#pragma unroll
        for (int reg = 0; reg < 4; ++reg) {
            int r = m * 16 + lg * 4 + reg;
            float v0 = acc[m][0][reg] + bias[0];
            float v1 = acc[m][1][reg] + bias[1];
            float v2 = acc[m][2][reg] + bias[2];
            float v3 = acc[m][3][reg] + bias[3];
            size_t rowoff = (m0 + r) * CC + w * 64 + l15;
            if (MODE == 3) {
                outf[rowoff + 0]  = v0; outf[rowoff + 16] = v1;
                outf[rowoff + 32] = v2; outf[rowoff + 48] = v3;
            } else {
                outb[rowoff + 0]  = f2b(v0); outb[rowoff + 16] = f2b(v1);
                outb[rowoff + 32] = f2b(v2); outb[rowoff + 48] = f2b(v3);
            }
        }
    }
}

// ---------------------------------------------------------------------------
// Standalone per-(row,head) softmax over 64 values, in place. Trivially
// correct: one thread owns one 64-value segment. grid = 2048 x 256.
// ---------------------------------------------------------------------------
__global__ __launch_bounds__(256) void softmax64(bf16* X)
{
    size_t idx = (size_t)blockIdx.x * 256 + threadIdx.x;  // [0, 524288)
    bf16* p = X + (idx >> 3) * CC + (idx & 7) * 64;
    float v[64];
    float mx = -1e30f;
#pragma unroll
    for (int k = 0; k < 8; ++k) {
        bf16x8 w = *(const bf16x8*)(p + k * 8);
#pragma unroll
        for (int j = 0; j < 8; ++j) { v[k * 8 + j] = b2f(w[j]); mx = fmaxf(mx, v[k * 8 + j]); }
    }
    float sm = 0.f;
#pragma unroll
    for (int i = 0; i < 64; ++i) { v[i] = __expf(v[i] - mx); sm += v[i]; }
    float inv = 1.0f / sm;
#pragma unroll
    for (int k = 0; k < 8; ++k) {
        bf16x8 w;
#pragma unroll
        for (int j = 0; j < 8; ++j) w[j] = f2b(v[k * 8 + j] * inv);
        *(bf16x8*)(p + k * 8) = w;
    }
}

// ---------------------------------------------------------------------------
// kv partials, scalar outer-product version. Block = (b,h,chunk of 2048 t).
// kv[d][e] = sum_t K[t,d]*V[t,e]; ksum[d] = sum_t K[t,d].
// part[(bh*8+chunk)][4160].  grid = 256 x 256.
// ---------------------------------------------------------------------------
__global__ __launch_bounds__(256) void kv_partial_simple(
    const bf16* __restrict__ Kb, const bf16* __restrict__ Vb,
    float* __restrict__ part)
{
    __shared__ float Ks[16][68], Vs[16][68];
    const int tid = threadIdx.x;
    const int bh = blockIdx.x >> 3, chunk = blockIdx.x & 7;
    const int b = bh >> 3, h = bh & 7;
    const size_t base = (size_t)b * TT * CC + h * 64;
    const int d0 = (tid & 15) * 4, e0 = (tid >> 4) * 4;

    float acc[4][4];
#pragma unroll
    for (int i = 0; i < 4; ++i)
#pragma unroll
        for (int j = 0; j < 4; ++j) acc[i][j] = 0.f;
    float ks[4] = {0.f, 0.f, 0.f, 0.f};

    const int tstart = chunk * 2048;
    for (int t0 = tstart; t0 < tstart + 2048; t0 += 16) {
        __syncthreads();
        {
            int idx = tid * 4;
            int t = idx >> 6, dc = idx & 63;
            const bf16* gk = Kb + base + (size_t)(t0 + t) * CC + dc;
            const bf16* gv = Vb + base + (size_t)(t0 + t) * CC + dc;
            bf16x4 k4 = *(const bf16x4*)gk;
            bf16x4 v4 = *(const bf16x4*)gv;
            *(float4*)&Ks[t][dc] = make_float4(b2f(k4[0]), b2f(k4[1]), b2f(k4[2]), b2f(k4[3]));
            *(float4*)&Vs[t][dc] = make_float4(b2f(v4[0]), b2f(v4[1]), b2f(v4[2]), b2f(v4[3]));
        }
        __syncthreads();
#pragma unroll 4
        for (int tt = 0; tt < 16; ++tt) {
            float kf[4], vf[4];
#pragma unroll
            for (int i = 0; i < 4; ++i) { kf[i] = Ks[tt][d0 + i]; vf[i] = Vs[tt][e0 + i]; }
            if (e0 == 0) {
#pragma unroll
                for (int i = 0; i < 4; ++i) ks[i] += kf[i];
            }
#pragma unroll
            for (int i = 0; i < 4; ++i)
#pragma unroll
                for (int j = 0; j < 4; ++j) acc[i][j] += kf[i] * vf[j];
        }
    }

    float* p = part + (size_t)blockIdx.x * 4160;
#pragma unroll
    for (int i = 0; i < 4; ++i)
#pragma unroll
        for (int j = 0; j < 4; ++j) p[(d0 + i) * 64 + (e0 + j)] = acc[i][j];
    if (tid < 16) {
#pragma unroll
        for (int i = 0; i < 4; ++i) p[4096 + d0 + i] = ks[i];
    }
}

// ---------------------------------------------------------------------------
// Reduce 8 partials per (b,h) -> kvT fp32 [bh][e][d] and ksum fp32 [bh][d].
// ---------------------------------------------------------------------------
__global__ __launch_bounds__(256) void kv_reduce(
    const float* __restrict__ part, float* __restrict__ kvT,
    float* __restrict__ ksum)
{
    const int bh = blockIdx.x;
    const int tid = threadIdx.x;
    const float* p0 = part + (size_t)bh * 8 * 4160;
    for (int i = tid; i < 4160; i += 256) {
        float s = 0.f;
        for (int c = 0; c < 8; ++c) s += p0[(size_t)c * 4160 + i];
        if (i < 4096) {
            int d = i >> 6, e = i & 63;
            kvT[(size_t)bh * 4096 + e * 64 + d] = s;   // [e][d]
        } else {
            ksum[bh * 64 + (i - 4096)] = s;
        }
    }
}

// ---------------------------------------------------------------------------
// A' = (q @ kv) * 1/(q . ksum), scalar version, in place over Qb.
// Block = 64 rows; loops heads; Q and kv staged in LDS.
// Thread (r = tid>>2, ec = tid&3) computes 16 outputs e in [ec*16, ec*16+16).
// grid = 1024 x 256.
// ---------------------------------------------------------------------------
__global__ __launch_bounds__(256) void qkv_norm_simple(
    bf16* Qb, const float* __restrict__ kvT, const float* __restrict__ ksum)
{
    __shared__ float Qs[64][68];    // [r][d]
    __shared__ float KVs[64][68];   // [d][e]
    __shared__ float ksm[8][64];
    const int tid = threadIdx.x;
    const size_t t0 = (size_t)blockIdx.x * 64;
    const int b = (int)(t0 / TT);
    const int r = tid >> 2, ec = tid & 3;

    for (int i = tid; i < 512; i += 256) ksm[i >> 6][i & 63] = ksum[b * 512 + i];

    for (int h = 0; h < 8; ++h) {
        __syncthreads();   // protect LDS from previous iteration's readers (and ksm for h=0)
        const float* kvb = kvT + (size_t)(b * 8 + h) * 4096;
#pragma unroll
        for (int rep = 0; rep < 4; ++rep) {
            int idx = (tid + rep * 256) * 4;
            int rr = idx >> 6, dc = idx & 63;
            bf16x4 q4 = *(const bf16x4*)(Qb + (t0 + rr) * CC + h * 64 + dc);
            *(float4*)&Qs[rr][dc] = make_float4(b2f(q4[0]), b2f(q4[1]), b2f(q4[2]), b2f(q4[3]));
            // kvT[e][d] -> KVs[d][e]
            float4 v4 = *(const float4*)(kvb + rr * 64 + dc);
            KVs[dc + 0][rr] = v4.x; KVs[dc + 1][rr] = v4.y;
            KVs[dc + 2][rr] = v4.z; KVs[dc + 3][rr] = v4.w;
        }
        __syncthreads();

        float acc[16];
#pragma unroll
        for (int i = 0; i < 16; ++i) acc[i] = 0.f;
        float dot = 0.f;
        for (int d = 0; d < 64; ++d) {
            float qv = Qs[r][d];
            dot += qv * ksm[h][d];
            const float* kr = &KVs[d][ec * 16];
            float4 a = *(const float4*)(kr + 0);
            float4 bq = *(const float4*)(kr + 4);
            float4 c = *(const float4*)(kr + 8);
            float4 dd = *(const float4*)(kr + 12);
            acc[0] += qv * a.x;  acc[1] += qv * a.y;  acc[2] += qv * a.z;  acc[3] += qv * a.w;
            acc[4] += qv * bq.x; acc[5] += qv * bq.y; acc[6] += qv * bq.z; acc[7] += qv * bq.w;
            acc[8] += qv * c.x;  acc[9] += qv * c.y;  acc[10] += qv * c.z; acc[11] += qv * c.w;
            acc[12] += qv * dd.x; acc[13] += qv * dd.y; acc[14] += qv * dd.z; acc[15] += qv * dd.w;
        }
        float dinv = 1.0f / dot;
        bf16* op = Qb + (t0 + r) * CC + h * 64 + ec * 16;
#pragma unroll
        for (int i = 0; i < 16; ++i) op[i] = f2b(acc[i] * dinv);
    }
}

// ---------------------------------------------------------------------------
extern "C" void kernel_launch(void* const* d_in, const int* in_sizes, int n_in,
                              void* d_out, int out_size, void* d_ws, size_t ws_size,
                              hipStream_t stream)
{
    const float* x1 = (const float*)d_in[0];
    const float* x2 = (const float*)d_in[1];
    const float* y0 = (const float*)d_in[2];
    const float* y1 = (const float*)d_in[3];
    const float* Wq = (const float*)d_in[4];
    const float* bq = (const float*)d_in[5];
    const float* Wk = (const float*)d_in[6];
    const float* bk = (const float*)d_in[7];
    const float* Wv = (const float*)d_in[8];
    const float* bv = (const float*)d_in[9];
    const float* Wp = (const float*)d_in[10];
    const float* bp = (const float*)d_in[11];
    (void)in_sizes; (void)n_in; (void)out_size; (void)ws_size;

    char* ws = (char*)d_ws;
    size_t off = 0;
    auto alloc = [&](size_t bytes) -> void* {
        void* p = ws + off;
        off += (bytes + 255) & ~(size_t)255;
        return p;
    };
    // ws footprint ~7.4 MB total. All big buffers live in d_out (134 MB):
    //   K -> half0, V -> half1; after kv is consumed, Q -> half0, A' in-place;
    //   final GEMM reads A' (first 67 MB as bf16) while writing fp32 output
    //   via descending halving phases (race-free by construction).
    bf16* WtQ  = (bf16*)alloc((size_t)512 * 512 * 2);
    bf16* WtK  = (bf16*)alloc((size_t)512 * 512 * 2);
    bf16* WtV0 = (bf16*)alloc((size_t)512 * 512 * 2);
    bf16* WtV1 = (bf16*)alloc((size_t)512 * 512 * 2);
    bf16* WtP  = (bf16*)alloc((size_t)512 * 512 * 2);
    float* ksum = (float*)alloc((size_t)32 * 64 * 4);
    float* kvT  = (float*)alloc((size_t)32 * 4096 * 4);
    float* part = (float*)alloc((size_t)256 * 4160 * 4);

    bf16* Kb = (bf16*)d_out;                          // 64 MB scratch in d_out
    bf16* Vb = Kb + (size_t)MTOT * CC;                // second 64 MB
    bf16* Qb = Kb;                                    // reuse after kv consumed
    float* outF = (float*)d_out;

    transpose_w<<<256, 256, 0, stream>>>(Wq, WtQ);
    transpose_w<<<256, 256, 0, stream>>>(Wk, WtK);
    transpose_w<<<256, 256, 0, stream>>>(Wv, WtV0);
    transpose_w<<<256, 256, 0, stream>>>(Wv + (size_t)512 * 512, WtV1);
    transpose_w<<<256, 256, 0, stream>>>(Wp, WtP);

    gemm_proj<1><<<MTOT / 64, 512, 0, stream>>>(x2, nullptr, nullptr, WtK, nullptr,
                                                bk, nullptr, Kb, nullptr, 0);
    softmax64<<<2048, 256, 0, stream>>>(Kb);
    gemm_proj<2><<<MTOT / 64, 512, 0, stream>>>(y0, y1, nullptr, WtV0, WtV1,
                                                bv, bv + 512, Vb, nullptr, 0);
    kv_partial_simple<<<256, 256, 0, stream>>>(Kb, Vb, part);
    kv_reduce<<<32, 256, 0, stream>>>(part, kvT, ksum);

    gemm_proj<1><<<MTOT / 64, 512, 0, stream>>>(x1, nullptr, nullptr, WtQ, nullptr,
                                                bq, nullptr, Qb, nullptr, 0);
    softmax64<<<2048, 256, 0, stream>>>(Qb);
    qkv_norm_simple<<<1024, 256, 0, stream>>>(Qb, kvT, ksum);

    // Phased final GEMM: phase k handles blocks [s, s+n); its output writes
    // only clobber A' rows consumed by earlier phases (or its own, post-read).
    const int starts[11] = {512, 256, 128, 64, 32, 16, 8, 4, 2, 1, 0};
    const int counts[11] = {512, 256, 128, 64, 32, 16, 8, 4, 2, 1, 1};
    for (int p = 0; p < 11; ++p) {
        gemm_proj<3><<<counts[p], 512, 0, stream>>>(nullptr, nullptr, (const bf16*)Qb,
                                                    WtP, nullptr, bp, nullptr,
                                                    nullptr, outF, starts[p]);
    }
}

// Round 6
// 644.816 us; speedup vs baseline: 1.3621x; 1.3621x over previous
//
#include <hip/hip_runtime.h>
#include <cstdint>
#include <cstddef>

#define BB 4
#define TT 16384
#define CC 512
#define HH 8
#define DD 64
#define MTOT (BB*TT)   // 65536 token rows

typedef __attribute__((ext_vector_type(4))) float f32x4;
typedef __bf16 bf16;
typedef __attribute__((ext_vector_type(8))) bf16 bf16x8;
typedef __attribute__((ext_vector_type(4))) bf16 bf16x4;

static __device__ __forceinline__ float b2f(bf16 x) { return (float)x; }
static __device__ __forceinline__ bf16  f2b(float x) { return (bf16)x; }

// ---------------------------------------------------------------------------
// Transpose+convert all five 512x512 fp32 weights to bf16 Wt[n][k] = W[k][n].
// Body VERIFIED r3; merged into one launch. grid = 5*256 x 256.
// ---------------------------------------------------------------------------
__global__ __launch_bounds__(256) void transpose_w5(
    const float* __restrict__ W0, const float* __restrict__ W1,
    const float* __restrict__ W2, const float* __restrict__ W3,
    const float* __restrict__ W4,
    bf16* __restrict__ T0, bf16* __restrict__ T1, bf16* __restrict__ T2,
    bf16* __restrict__ T3, bf16* __restrict__ T4)
{
    __shared__ float tile[32][33];
    const int which = blockIdx.x >> 8;
    const float* W = which == 0 ? W0 : which == 1 ? W1 : which == 2 ? W2
                   : which == 3 ? W3 : W4;
    bf16* Wt = which == 0 ? T0 : which == 1 ? T1 : which == 2 ? T2
             : which == 3 ? T3 : T4;
    const int t = blockIdx.x & 255;
    const int r0 = (t >> 4) * 32, c0 = (t & 15) * 32;
    const int tid = threadIdx.x;
    {
        int r = tid >> 3, c4 = (tid & 7) << 2;
        float4 v = *(const float4*)(W + (size_t)(r0 + r) * 512 + c0 + c4);
        tile[r][c4 + 0] = v.x; tile[r][c4 + 1] = v.y;
        tile[r][c4 + 2] = v.z; tile[r][c4 + 3] = v.w;
    }
    __syncthreads();
    {
        int n = tid >> 3, k4 = (tid & 7) << 2;
        bf16x4 o;
        o[0] = f2b(tile[k4 + 0][n]); o[1] = f2b(tile[k4 + 1][n]);
        o[2] = f2b(tile[k4 + 2][n]); o[3] = f2b(tile[k4 + 3][n]);
        *(bf16x4*)(Wt + (size_t)(c0 + n) * 512 + r0 + k4) = o;
    }
}

// ---------------------------------------------------------------------------
// Projection GEMM (MFMA). Core + MODE 2/3 VERIFIED r3. MODE 0 = fused
// per-64-col-head softmax epilogue (exonerated by r1==r4 absmax equivalence).
// MODE 0: fp32 A, softmax over each head's 64 cols, store bf16 (Q/K)
// MODE 2: two fp32 A / two weights (K=1024), +bias0+bias1, store bf16 (V)
// MODE 3: bf16 A, +bias, store fp32 (final out; m_base for phased launches)
// ---------------------------------------------------------------------------
template<int MODE>
__global__ __launch_bounds__(512) void gemm_proj(
    const float* A0, const float* A1, const bf16* Abf,
    const bf16* Wt0, const bf16* Wt1,
    const float* bias0, const float* bias1,
    bf16* outb, float* outf, int m_base)
{
    __shared__ bf16 Asm[64][40];
    __shared__ bf16 Bsm[512][40];

    const int tid = threadIdx.x;
    const int lane = tid & 63;
    const int w = tid >> 6;
    const int l15 = lane & 15, lg = lane >> 4;
    const size_t m0 = (size_t)(blockIdx.x + m_base) * 64;

    f32x4 acc[4][4];
#pragma unroll
    for (int m = 0; m < 4; ++m)
#pragma unroll
        for (int n = 0; n < 4; ++n) acc[m][n] = (f32x4){0.f, 0.f, 0.f, 0.f};

    const int KSTEPS = (MODE == 2) ? 32 : 16;
    for (int ko = 0; ko < KSTEPS; ++ko) {
        const int k0 = (ko & 15) * 32;
        const float* Af = (MODE == 2 && ko >= 16) ? A1 : A0;
        const bf16* Wt  = (MODE == 2 && ko >= 16) ? Wt1 : Wt0;
        __syncthreads();
        if (MODE == 3) {
            if (tid < 256) {
                int row = tid >> 2, c8 = (tid & 3) << 3;
                bf16x8 v = *(const bf16x8*)(Abf + (m0 + row) * CC + k0 + c8);
                *(bf16x8*)&Asm[row][c8] = v;
            }
        } else {
            int row = tid >> 3, c4 = (tid & 7) << 2;
            float4 v = *(const float4*)(Af + (m0 + row) * CC + k0 + c4);
            bf16x4 s;
            s[0] = f2b(v.x); s[1] = f2b(v.y); s[2] = f2b(v.z); s[3] = f2b(v.w);
            *(bf16x4*)&Asm[row][c4] = s;
        }
#pragma unroll
        for (int r = 0; r < 4; ++r) {
            int n = (tid >> 2) + (r << 7), kk = (tid & 3) << 3;
            bf16x8 v = *(const bf16x8*)(Wt + (size_t)n * CC + k0 + kk);
            *(bf16x8*)&Bsm[n][kk] = v;
        }
        __syncthreads();
        bf16x8 af[4], bfv[4];
#pragma unroll
        for (int m = 0; m < 4; ++m)
            af[m] = *(const bf16x8*)&Asm[m * 16 + l15][lg * 8];
#pragma unroll
        for (int n = 0; n < 4; ++n)
            bfv[n] = *(const bf16x8*)&Bsm[w * 64 + n * 16 + l15][lg * 8];
#pragma unroll
        for (int m = 0; m < 4; ++m)
#pragma unroll
            for (int n = 0; n < 4; ++n)
                acc[m][n] = __builtin_amdgcn_mfma_f32_16x16x32_bf16(
                    af[m], bfv[n], acc[m][n], 0, 0, 0);
    }

    float bias[4];
#pragma unroll
    for (int n = 0; n < 4; ++n) {
        int col = w * 64 + n * 16 + l15;
        float bvv = bias0 ? bias0[col] : 0.f;
        if (MODE == 2) bvv += bias1[col];
        bias[n] = bvv;
    }
#pragma unroll
    for (int m = 0; m < 4; ++m) {
#pragma unroll
        for (int reg = 0; reg < 4; ++reg) {
            int r = m * 16 + lg * 4 + reg;
            float v0 = acc[m][0][reg] + bias[0];
            float v1 = acc[m][1][reg] + bias[1];
            float v2 = acc[m][2][reg] + bias[2];
            float v3 = acc[m][3][reg] + bias[3];
            if (MODE == 0) {
                // softmax over this row's 64 head cols: row = m*16+lg*4+reg is
                // held by the 16 consecutive lanes sharing lg (l15=0..15),
                // 4 col-values each; shfl_xor s<16 stays in that group.
                float mx = fmaxf(fmaxf(v0, v1), fmaxf(v2, v3));
#pragma unroll
                for (int s = 1; s < 16; s <<= 1) mx = fmaxf(mx, __shfl_xor(mx, s, 64));
                v0 = __expf(v0 - mx); v1 = __expf(v1 - mx);
                v2 = __expf(v2 - mx); v3 = __expf(v3 - mx);
                float sm = v0 + v1 + v2 + v3;
#pragma unroll
                for (int s = 1; s < 16; s <<= 1) sm += __shfl_xor(sm, s, 64);
                float inv = 1.0f / sm;
                v0 *= inv; v1 *= inv; v2 *= inv; v3 *= inv;
            }
            size_t rowoff = (m0 + r) * CC + w * 64 + l15;
            if (MODE == 3) {
                outf[rowoff + 0]  = v0; outf[rowoff + 16] = v1;
                outf[rowoff + 32] = v2; outf[rowoff + 48] = v3;
            } else {
                outb[rowoff + 0]  = f2b(v0); outb[rowoff + 16] = f2b(v1);
                outb[rowoff + 32] = f2b(v2); outb[rowoff + 48] = f2b(v3);
            }
        }
    }
}

// ---------------------------------------------------------------------------
// kv partials, scalar outer-product (r3-VERIFIED structure, retiled for
// occupancy: 32 chunks/bh of 512 t, 32-t LDS rounds).
// kv[d][e] = sum_t K[t,d]*V[t,e]; ksum[d] = sum_t K[t,d].
// part[blockIdx.x][4160].  grid = 1024 x 256 (4 blocks/CU).
// ---------------------------------------------------------------------------
__global__ __launch_bounds__(256) void kv_partial2(
    const bf16* __restrict__ Kb, const bf16* __restrict__ Vb,
    float* __restrict__ part)
{
    __shared__ float Ks[32][68], Vs[32][68];
    const int tid = threadIdx.x;
    const int bh = blockIdx.x >> 5, chunk = blockIdx.x & 31;
    const int b = bh >> 3, h = bh & 7;
    const size_t base = (size_t)b * TT * CC + h * 64;
    const int d0 = (tid & 15) * 4, e0 = (tid >> 4) * 4;

    float acc[4][4];
#pragma unroll
    for (int i = 0; i < 4; ++i)
#pragma unroll
        for (int j = 0; j < 4; ++j) acc[i][j] = 0.f;
    float ks[4] = {0.f, 0.f, 0.f, 0.f};

    const int tstart = chunk * 512;
    for (int t0 = tstart; t0 < tstart + 512; t0 += 32) {
        __syncthreads();
#pragma unroll
        for (int rep = 0; rep < 2; ++rep) {
            int idx = (tid + rep * 256) * 4;           // [0, 2048)
            int t = idx >> 6, dc = idx & 63;           // t in [0,32)
            const bf16* gk = Kb + base + (size_t)(t0 + t) * CC + dc;
            const bf16* gv = Vb + base + (size_t)(t0 + t) * CC + dc;
            bf16x4 k4 = *(const bf16x4*)gk;
            bf16x4 v4 = *(const bf16x4*)gv;
            *(float4*)&Ks[t][dc] = make_float4(b2f(k4[0]), b2f(k4[1]), b2f(k4[2]), b2f(k4[3]));
            *(float4*)&Vs[t][dc] = make_float4(b2f(v4[0]), b2f(v4[1]), b2f(v4[2]), b2f(v4[3]));
        }
        __syncthreads();
#pragma unroll 8
        for (int tt = 0; tt < 32; ++tt) {
            float kf[4], vf[4];
#pragma unroll
            for (int i = 0; i < 4; ++i) { kf[i] = Ks[tt][d0 + i]; vf[i] = Vs[tt][e0 + i]; }
            if (e0 == 0) {
#pragma unroll
                for (int i = 0; i < 4; ++i) ks[i] += kf[i];
            }
#pragma unroll
            for (int i = 0; i < 4; ++i)
#pragma unroll
                for (int j = 0; j < 4; ++j) acc[i][j] += kf[i] * vf[j];
        }
    }

    float* p = part + (size_t)blockIdx.x * 4160;
#pragma unroll
    for (int i = 0; i < 4; ++i)
#pragma unroll
        for (int j = 0; j < 4; ++j) p[(d0 + i) * 64 + (e0 + j)] = acc[i][j];
    if (tid < 16) {
#pragma unroll
        for (int i = 0; i < 4; ++i) p[4096 + d0 + i] = ks[i];
    }
}

// ---------------------------------------------------------------------------
// Reduce 32 partials per (b,h) -> kvT fp32 [bh][e][d] + ksum fp32 [bh][d].
// (r3-VERIFIED body; c-loop count 8->32.)  grid = 32 x 256.
// ---------------------------------------------------------------------------
__global__ __launch_bounds__(256) void kv_reduce(
    const float* __restrict__ part, float* __restrict__ kvT,
    float* __restrict__ ksum)
{
    const int bh = blockIdx.x;
    const int tid = threadIdx.x;
    const float* p0 = part + (size_t)bh * 32 * 4160;
    for (int i = tid; i < 4160; i += 256) {
        float s = 0.f;
        for (int c = 0; c < 32; ++c) s += p0[(size_t)c * 4160 + i];
        if (i < 4096) {
            int d = i >> 6, e = i & 63;
            kvT[(size_t)bh * 4096 + e * 64 + d] = s;   // [e][d]
        } else {
            ksum[bh * 64 + (i - 4096)] = s;
        }
    }
}

// ---------------------------------------------------------------------------
// A' = (q @ kv) * 1/(q . ksum), scalar, in place over Qb (r3-VERIFIED
// skeleton; thread tile 1x16 -> 4x4 for 2.2 FMA/LDS-read).
// Thread (rg=tid>>4, cg=tid&15) computes rows rg*4..+3 x cols cg*4..+3.
// grid = 1024 x 256.
// ---------------------------------------------------------------------------
__global__ __launch_bounds__(256) void qkv_norm2(
    bf16* Qb, const float* __restrict__ kvT, const float* __restrict__ ksum)
{
    __shared__ float Qs[64][68];    // [r][d]
    __shared__ float KVs[64][68];   // [d][e]
    __shared__ float ksm[8][64];
    const int tid = threadIdx.x;
    const size_t t0 = (size_t)blockIdx.x * 64;
    const int b = (int)(t0 / TT);
    const int rg = tid >> 4, cg = tid & 15;

    for (int i = tid; i < 512; i += 256) ksm[i >> 6][i & 63] = ksum[b * 512 + i];

    for (int h = 0; h < 8; ++h) {
        __syncthreads();   // protect LDS from prev readers (and ksm for h=0)
        const float* kvb = kvT + (size_t)(b * 8 + h) * 4096;
#pragma unroll
        for (int rep = 0; rep < 4; ++rep) {
            int idx = (tid + rep * 256) * 4;
            int rr = idx >> 6, dc = idx & 63;
            bf16x4 q4 = *(const bf16x4*)(Qb + (t0 + rr) * CC + h * 64 + dc);
            *(float4*)&Qs[rr][dc] = make_float4(b2f(q4[0]), b2f(q4[1]), b2f(q4[2]), b2f(q4[3]));
            float4 v4 = *(const float4*)(kvb + rr * 64 + dc);   // kvT[e][d] -> KVs[d][e]
            KVs[dc + 0][rr] = v4.x; KVs[dc + 1][rr] = v4.y;
            KVs[dc + 2][rr] = v4.z; KVs[dc + 3][rr] = v4.w;
        }
        __syncthreads();

        float acc[4][4];
#pragma unroll
        for (int i = 0; i < 4; ++i)
#pragma unroll
            for (int j = 0; j < 4; ++j) acc[i][j] = 0.f;
        float dot[4] = {0.f, 0.f, 0.f, 0.f};

        for (int d = 0; d < 64; ++d) {
            float ksd = ksm[h][d];
            float4 kv4 = *(const float4*)&KVs[d][cg * 4];
            float q[4];
#pragma unroll
            for (int i = 0; i < 4; ++i) {
                q[i] = Qs[rg * 4 + i][d];
                dot[i] += q[i] * ksd;
            }
#pragma unroll
            for (int i = 0; i < 4; ++i) {
                acc[i][0] += q[i] * kv4.x; acc[i][1] += q[i] * kv4.y;
                acc[i][2] += q[i] * kv4.z; acc[i][3] += q[i] * kv4.w;
            }
        }
#pragma unroll
        for (int i = 0; i < 4; ++i) {
            float dinv = 1.0f / dot[i];
            bf16x4 o;
#pragma unroll
            for (int j = 0; j < 4; ++j) o[j] = f2b(acc[i][j] * dinv);
            *(bf16x4*)(Qb + (t0 + rg * 4 + i) * CC + h * 64 + cg * 4) = o;
        }
    }
}

// ---------------------------------------------------------------------------
extern "C" void kernel_launch(void* const* d_in, const int* in_sizes, int n_in,
                              void* d_out, int out_size, void* d_ws, size_t ws_size,
                              hipStream_t stream)
{
    const float* x1 = (const float*)d_in[0];
    const float* x2 = (const float*)d_in[1];
    const float* y0 = (const float*)d_in[2];
    const float* y1 = (const float*)d_in[3];
    const float* Wq = (const float*)d_in[4];
    const float* bq = (const float*)d_in[5];
    const float* Wk = (const float*)d_in[6];
    const float* bk = (const float*)d_in[7];
    const float* Wv = (const float*)d_in[8];
    const float* bv = (const float*)d_in[9];
    const float* Wp = (const float*)d_in[10];
    const float* bp = (const float*)d_in[11];
    (void)in_sizes; (void)n_in; (void)out_size; (void)ws_size;

    char* ws = (char*)d_ws;
    size_t off = 0;
    auto alloc = [&](size_t bytes) -> void* {
        void* p = ws + off;
        off += (bytes + 255) & ~(size_t)255;
        return p;
    };
    // ws ~22 MB. Big buffers in d_out (134 MB): K->half0, V->half1; then
    // Q->half0, A' in-place; phased final GEMM (verified r3) + 2MB head copy.
    bf16* WtQ  = (bf16*)alloc((size_t)512 * 512 * 2);
    bf16* WtK  = (bf16*)alloc((size_t)512 * 512 * 2);
    bf16* WtV0 = (bf16*)alloc((size_t)512 * 512 * 2);
    bf16* WtV1 = (bf16*)alloc((size_t)512 * 512 * 2);
    bf16* WtP  = (bf16*)alloc((size_t)512 * 512 * 2);
    float* ksum = (float*)alloc((size_t)32 * 64 * 4);
    float* kvT  = (float*)alloc((size_t)32 * 4096 * 4);
    float* part = (float*)alloc((size_t)1024 * 4160 * 4);
    bf16* Acopy = (bf16*)alloc((size_t)32 * 64 * CC * 2);   // A' blocks [0,32)

    bf16* Kb = (bf16*)d_out;                          // 64 MB scratch in d_out
    bf16* Vb = Kb + (size_t)MTOT * CC;                // second 64 MB
    bf16* Qb = Kb;                                    // reuse after kv consumed
    float* outF = (float*)d_out;

    transpose_w5<<<1280, 256, 0, stream>>>(Wq, Wk, Wv, Wv + (size_t)512 * 512, Wp,
                                           WtQ, WtK, WtV0, WtV1, WtP);

    gemm_proj<0><<<MTOT / 64, 512, 0, stream>>>(x2, nullptr, nullptr, WtK, nullptr,
                                                bk, nullptr, Kb, nullptr, 0);
    gemm_proj<2><<<MTOT / 64, 512, 0, stream>>>(y0, y1, nullptr, WtV0, WtV1,
                                                bv, bv + 512, Vb, nullptr, 0);
    kv_partial2<<<1024, 256, 0, stream>>>(Kb, Vb, part);
    kv_reduce<<<32, 256, 0, stream>>>(part, kvT, ksum);

    gemm_proj<0><<<MTOT / 64, 512, 0, stream>>>(x1, nullptr, nullptr, WtQ, nullptr,
                                                bq, nullptr, Qb, nullptr, 0);
    qkv_norm2<<<1024, 256, 0, stream>>>(Qb, kvT, ksum);

    // Copy A' blocks [0,32) (first 2 MB) aside, then phased final GEMM:
    // descending phases; phase writing fp32 blocks [s,s+n) clobbers bf16
    // blocks [2s,2(s+n)), already consumed by the previous phase. Last
    // phase [0,32) reads the copy.
    hipMemcpyAsync(Acopy, Qb, (size_t)32 * 64 * CC * 2, hipMemcpyDeviceToDevice,
                   stream);
    const int starts[5] = {512, 256, 128, 64, 32};
    const int counts[5] = {512, 256, 128, 64, 32};
    for (int p = 0; p < 5; ++p) {
        gemm_proj<3><<<counts[p], 512, 0, stream>>>(nullptr, nullptr, (const bf16*)Qb,
                                                    WtP, nullptr, bp, nullptr,
                                                    nullptr, outF, starts[p]);
    }
    gemm_proj<3><<<32, 512, 0, stream>>>(nullptr, nullptr, (const bf16*)Acopy,
                                         WtP, nullptr, bp, nullptr,
                                         nullptr, outF, 0);
}